// Round 12
// baseline (204.109 us; speedup 1.0000x reference)
//
#include <hip/hip_runtime.h>
#include <hip/hip_fp16.h>
#include <type_traits>

// 3-layer GCN encoder on MI355X.
//   CSR build: bin (bucket by dst>>8, packed src|localdst<<16) ->
//              build_csr (fused bucket-scan + LDS histogram + block scan -> off/dinv,
//                         then in-LDS scatter -> col)
//   Per layer: g = (h @ W) * dinv [fp16] ; h = act(dinv * sum_{N(d)+self} g[s] + b)
// R12: agg gather unrolled 8-deep (8 independent accumulator chains, 8 row loads
//      + 8 col broadcasts in flight/lane; was 4). R11 confirmed aggs are
//      latency-bound: concurrency x2 gave -23us at constant instruction count.
// NOTE: packing assumes N <= 65535 (here N=50000).

#define IN_DIM 64
#define HID_DIM 64
#define LAT_DIM 32
#define BCAP 5120   // bucket capacity: mean 4081, sigma ~64 -> +16 sigma

typedef __attribute__((ext_vector_type(8))) _Float16 half8;
typedef __attribute__((ext_vector_type(4))) _Float16 half4;

// ---------------- bucketed CSR construction ----------------

__global__ __launch_bounds__(256) void bin_kernel(const int* __restrict__ src,
                                                  const int* __restrict__ dst,
                                                  int* __restrict__ bucket_cnt,
                                                  unsigned* __restrict__ pairs, int E) {
    __shared__ int bcnt[256];
    __shared__ int bbase[256];
    int tid = threadIdx.x;
    bcnt[tid] = 0;
    __syncthreads();
    int base = blockIdx.x * 4096;
    unsigned pk[16]; int bk[16]; int rk[16];
    #pragma unroll
    for (int i = 0; i < 16; ++i) {
        int e = base + i * 256 + tid;
        bk[i] = -1;
        if (e < E) {
            int s = __builtin_nontemporal_load(src + e);
            int d = __builtin_nontemporal_load(dst + e);
            bk[i] = d >> 8;
            pk[i] = (unsigned)s | ((unsigned)(d & 255) << 16);
            rk[i] = atomicAdd(&bcnt[bk[i]], 1);
        }
    }
    __syncthreads();
    int c = bcnt[tid];
    if (c > 0) bbase[tid] = atomicAdd(&bucket_cnt[tid], c);
    __syncthreads();
    #pragma unroll
    for (int i = 0; i < 16; ++i) {
        if (bk[i] >= 0) {
            int pos = bbase[bk[i]] + rk[i];
            if (pos < BCAP) pairs[(size_t)bk[i] * BCAP + pos] = pk[i];
        }
    }
}

// Fused: (A) every block scans all bucket counts in LDS (cheap, redundant),
// (B) per-bucket node histogram, (C) block scan -> off/dinv, (D) in-LDS scatter.
__global__ __launch_bounds__(256) void build_csr_kernel(const unsigned* __restrict__ pairs,
                                                        const int* __restrict__ bucket_cnt,
                                                        int* __restrict__ off,
                                                        float* __restrict__ dinv,
                                                        int* __restrict__ col,
                                                        int N, int NBK) {
    __shared__ int sboff[256];
    __shared__ int h[256];
    __shared__ int scur[256];
    __shared__ int wtot[4];
    int b = blockIdx.x, tid = threadIdx.x;
    int lane = tid & 63, wid = tid >> 6;

    // A: exclusive scan of bucket counts
    int v = (tid < NBK) ? min(bucket_cnt[tid], BCAP) : 0;
    int sc = v;
    #pragma unroll
    for (int d = 1; d < 64; d <<= 1) {
        int t = __shfl_up(sc, d, 64);
        if (lane >= d) sc += t;
    }
    if (lane == 63) wtot[wid] = sc;
    h[tid] = 0;
    __syncthreads();
    int woff = 0;
    #pragma unroll
    for (int w = 0; w < 4; ++w) if (w < wid) woff += wtot[w];
    sboff[tid] = woff + sc - v;
    __syncthreads();
    int boff_b = sboff[b];

    // B: histogram of this bucket's local dst
    int c = min(bucket_cnt[b], BCAP);
    const unsigned* pb = pairs + (size_t)b * BCAP;
    for (int i = tid; i < c; i += 256)
        atomicAdd(&h[pb[i] >> 16], 1);
    __syncthreads();

    // C: block scan of histogram -> off / dinv / scur
    int hv = h[tid];
    int sc2 = hv;
    #pragma unroll
    for (int d = 1; d < 64; d <<= 1) {
        int t = __shfl_up(sc2, d, 64);
        if (lane >= d) sc2 += t;
    }
    if (lane == 63) wtot[wid] = sc2;
    __syncthreads();
    int woff2 = 0;
    #pragma unroll
    for (int w = 0; w < 4; ++w) if (w < wid) woff2 += wtot[w];
    int incl = woff2 + sc2;
    int node = b * 256 + tid;
    scur[tid] = boff_b + incl - hv;
    if (node < N) {
        off[node + 1] = boff_b + incl;
        dinv[node]    = rsqrtf((float)(hv + 1));
    }
    if (b == 0 && tid == 0) off[0] = 0;
    __syncthreads();

    // D: scatter (col writes land in this bucket's contiguous window)
    for (int i = tid; i < c; i += 256) {
        unsigned p = pb[i];
        int pos = atomicAdd(&scur[p >> 16], 1);
        col[pos] = (int)(p & 0xFFFFu);
    }
}

// ---------------- GEMM (N x 64) @ (64 x OUT) * dinv[row] -> fp16 G ----------------
// Row-major X staging (coalesced). 4x4 outputs/thread; a-reads are 16-lane
// broadcasts (free), b-read one 2-way b128 (free).

template<int OUT, int RT, typename TIN>
__global__ __launch_bounds__(256) void gemm_tile_kernel(const TIN* __restrict__ X,
                                                        const float* __restrict__ W,
                                                        const float* __restrict__ dinv,
                                                        _Float16* __restrict__ G, int N) {
    constexpr int CG = OUT / 4;
    static_assert(256 / CG * 4 == RT, "RT must match 4*(256/CG)");
    __shared__ float Ws[64 * OUT];
    __shared__ float Xs[RT][64 + 4];
    int tid = threadIdx.x;
    int row0 = blockIdx.x * RT;

    for (int f = 4 * tid; f < 64 * OUT; f += 1024)
        *(float4*)&Ws[f] = *(const float4*)&W[f];

    if constexpr (std::is_same<TIN, float>::value) {
        for (int f = 4 * tid; f < RT * 64; f += 1024) {
            int r = f >> 6, k0 = f & 63, gr = row0 + r;
            float4 v = (gr < N) ? *(const float4*)&X[(size_t)gr * 64 + k0]
                                : make_float4(0.f, 0.f, 0.f, 0.f);
            *(float4*)&Xs[r][k0] = v;
        }
    } else {
        for (int f = 8 * tid; f < RT * 64; f += 2048) {
            int r = f >> 6, k0 = f & 63, gr = row0 + r;
            if (gr < N) {
                half8 v = *(const half8*)&X[(size_t)gr * 64 + k0];
                #pragma unroll
                for (int i = 0; i < 8; ++i) Xs[r][k0 + i] = (float)v[i];
            } else {
                #pragma unroll
                for (int i = 0; i < 8; ++i) Xs[r][k0 + i] = 0.f;
            }
        }
    }
    __syncthreads();

    int cr = tid % CG;
    int rr = tid / CG;
    float acc[4][4] = {};
    #pragma unroll 4
    for (int k = 0; k < 64; ++k) {
        float4 bv = *(float4*)&Ws[k * OUT + 4 * cr];
        float av[4] = {Xs[4 * rr + 0][k], Xs[4 * rr + 1][k],
                       Xs[4 * rr + 2][k], Xs[4 * rr + 3][k]};
        float bb[4] = {bv.x, bv.y, bv.z, bv.w};
        #pragma unroll
        for (int j = 0; j < 4; ++j)
            #pragma unroll
            for (int i = 0; i < 4; ++i)
                acc[j][i] += av[j] * bb[i];
    }

    #pragma unroll
    for (int j = 0; j < 4; ++j) {
        int gr = row0 + 4 * rr + j;
        if (gr < N) {
            float s = dinv[gr];
            half4 o;
            #pragma unroll
            for (int i = 0; i < 4; ++i) o[i] = (_Float16)(acc[j][i] * s);
            *(half4*)&G[(size_t)gr * OUT + 4 * cr] = o;
        }
    }
}

// ---------------- CSR aggregation, half2 lanes, multi-node waves ----------------
// D=64: 2 nodes/wave (lanes 0-31 node A, 32-63 node B; lane owns one half2 pair).
// 8-deep unroll: 8 independent accumulator chains, 8 row gathers + 8 col
// broadcasts in flight per lane (R11 confirmed latency-bound; this doubles MLP).

template<bool TANH>
__global__ __launch_bounds__(256) void agg64_kernel(const _Float16* __restrict__ G,
                           const int* __restrict__ off, const int* __restrict__ col,
                           const float* __restrict__ dinv, const float* __restrict__ b,
                           _Float16* __restrict__ H, int N) {
    int tid  = threadIdx.x;
    int lane = tid & 63;
    int w    = tid >> 6;
    int half = lane >> 5;
    int l2   = lane & 31;                       // half2 column index (row = 32 half2)
    int node = (blockIdx.x * 4 + w) * 2 + half;
    if (node >= N) return;
    const __half2* Gv = (const __half2*)G;
    int p  = off[node];
    int p1 = off[node + 1];
    float ax[8], ay[8];
    #pragma unroll
    for (int i = 0; i < 8; ++i) { ax[i] = 0.f; ay[i] = 0.f; }
    {   // self loop
        float2 sf = __half22float2(Gv[(size_t)node * 32 + l2]);
        ax[0] = sf.x; ay[0] = sf.y;
    }
    for (; p + 7 < p1; p += 8) {
        int s[8];
        #pragma unroll
        for (int i = 0; i < 8; ++i) s[i] = col[p + i];
        #pragma unroll
        for (int i = 0; i < 8; ++i) {
            float2 v = __half22float2(Gv[(size_t)s[i] * 32 + l2]);
            ax[i] += v.x; ay[i] += v.y;
        }
    }
    for (; p < p1; ++p) {
        float2 v = __half22float2(Gv[(size_t)col[p] * 32 + l2]);
        ax[0] += v.x; ay[0] += v.y;
    }
    float sx = ((ax[0] + ax[1]) + (ax[2] + ax[3])) + ((ax[4] + ax[5]) + (ax[6] + ax[7]));
    float sy = ((ay[0] + ay[1]) + (ay[2] + ay[3])) + ((ay[4] + ay[5]) + (ay[6] + ay[7]));
    float dn = dinv[node];
    float vx = dn * sx + b[2 * l2 + 0];
    float vy = dn * sy + b[2 * l2 + 1];
    if (TANH) { vx = tanhf(vx); vy = tanhf(vy); }
    ((__half2*)H)[(size_t)node * 32 + l2] = __floats2half2_rn(vx, vy);
}

// D=32 final layer: 4 nodes/wave (16 lanes x half2 each), f32 float2 output.
__global__ __launch_bounds__(256) void agg32_kernel(const _Float16* __restrict__ G,
                           const int* __restrict__ off, const int* __restrict__ col,
                           const float* __restrict__ dinv, const float* __restrict__ b,
                           float* __restrict__ H, int N) {
    int tid  = threadIdx.x;
    int lane = tid & 63;
    int w    = tid >> 6;
    int q    = lane >> 4;                       // node within wave (0..3)
    int l2   = lane & 15;                       // half2 column index (row = 16 half2)
    int node = (blockIdx.x * 4 + w) * 4 + q;
    if (node >= N) return;
    const __half2* Gv = (const __half2*)G;
    int p  = off[node];
    int p1 = off[node + 1];
    float ax[8], ay[8];
    #pragma unroll
    for (int i = 0; i < 8; ++i) { ax[i] = 0.f; ay[i] = 0.f; }
    {   // self loop
        float2 sf = __half22float2(Gv[(size_t)node * 16 + l2]);
        ax[0] = sf.x; ay[0] = sf.y;
    }
    for (; p + 7 < p1; p += 8) {
        int s[8];
        #pragma unroll
        for (int i = 0; i < 8; ++i) s[i] = col[p + i];
        #pragma unroll
        for (int i = 0; i < 8; ++i) {
            float2 v = __half22float2(Gv[(size_t)s[i] * 16 + l2]);
            ax[i] += v.x; ay[i] += v.y;
        }
    }
    for (; p < p1; ++p) {
        float2 v = __half22float2(Gv[(size_t)col[p] * 16 + l2]);
        ax[0] += v.x; ay[0] += v.y;
    }
    float sx = ((ax[0] + ax[1]) + (ax[2] + ax[3])) + ((ax[4] + ax[5]) + (ax[6] + ax[7]));
    float sy = ((ay[0] + ay[1]) + (ay[2] + ay[3])) + ((ay[4] + ay[5]) + (ay[6] + ay[7]));
    float dn = dinv[node];
    float vx = dn * sx + b[2 * l2 + 0];
    float vy = dn * sy + b[2 * l2 + 1];
    ((float2*)H)[(size_t)node * 16 + l2] = make_float2(vx, vy);
}

// ---------------- launch ----------------

static inline size_t align256(size_t x) { return (x + 255) & ~(size_t)255; }

extern "C" void kernel_launch(void* const* d_in, const int* in_sizes, int n_in,
                              void* d_out, int out_size, void* d_ws, size_t ws_size,
                              hipStream_t stream) {
    const float* x   = (const float*)d_in[0];
    const int*   ei  = (const int*)d_in[1];
    const float* W1  = (const float*)d_in[2];
    const float* b1  = (const float*)d_in[3];
    const float* W2  = (const float*)d_in[4];
    const float* b2  = (const float*)d_in[5];
    const float* W3  = (const float*)d_in[6];
    const float* b3  = (const float*)d_in[7];
    float* out = (float*)d_out;

    const int N = in_sizes[0] / IN_DIM;   // 50000
    const int E = in_sizes[1] / 2;        // 800000
    const int* src = ei;
    const int* dst = ei + E;
    const int NBK  = (N + 255) / 256;     // buckets (196)
    const int BINB = (E + 4095) / 4096;   // bin blocks (196)

    // workspace layout
    char* ws = (char*)d_ws;
    size_t o = 0;
    int*       bkcnt = (int*)(ws + o);       o = align256(o + 256 * 4);
    int*       off   = (int*)(ws + o);       o = align256(o + (size_t)(N + 1) * 4);
    float*     dinv  = (float*)(ws + o);     o = align256(o + (size_t)N * 4);
    unsigned*  pairs = (unsigned*)(ws + o);  o = align256(o + (size_t)NBK * BCAP * 4);
    int*       col   = (int*)(ws + o);       o = align256(o + (size_t)E * 4);
    _Float16*  bufG  = (_Float16*)(ws + o);  o = align256(o + (size_t)N * HID_DIM * 2);
    _Float16*  bufH  = (_Float16*)(ws + o);  o = align256(o + (size_t)N * HID_DIM * 2);
    (void)ws_size;

    // CSR build
    hipMemsetAsync(bkcnt, 0, 256 * 4, stream);
    bin_kernel<<<BINB, 256, 0, stream>>>(src, dst, bkcnt, pairs, E);
    build_csr_kernel<<<NBK, 256, 0, stream>>>(pairs, bkcnt, off, dinv, col, N, NBK);

    const int g64_grid   = (N + 63) / 64;    // RT=64
    const int g32_grid   = (N + 127) / 128;  // RT=128
    const int agg64_grid = (N + 7) / 8;      // 2 nodes/wave, 4 waves/block
    const int agg32_grid = (N + 15) / 16;    // 4 nodes/wave, 4 waves/block

    // layer 1
    gemm_tile_kernel<HID_DIM, 64, float><<<g64_grid, 256, 0, stream>>>(x, W1, dinv, bufG, N);
    agg64_kernel<true><<<agg64_grid, 256, 0, stream>>>(bufG, off, col, dinv, b1, bufH, N);
    // layer 2
    gemm_tile_kernel<HID_DIM, 64, _Float16><<<g64_grid, 256, 0, stream>>>(bufH, W2, dinv, bufG, N);
    agg64_kernel<true><<<agg64_grid, 256, 0, stream>>>(bufG, off, col, dinv, b2, bufH, N);
    // layer 3 (D=32, f32 out)
    gemm_tile_kernel<LAT_DIM, 128, _Float16><<<g32_grid, 256, 0, stream>>>(bufH, W3, dinv, bufG, N);
    agg32_kernel<<<agg32_grid, 256, 0, stream>>>(bufG, off, col, dinv, b3, out, N);
}

// Round 14
// 197.019 us; speedup vs baseline: 1.0360x; 1.0360x over previous
//
#include <hip/hip_runtime.h>
#include <hip/hip_fp16.h>
#include <type_traits>

// 3-layer GCN encoder on MI355X.
//   CSR build: bin (bucket by dst>>8, packed src|localdst<<16) ->
//              build_csr (fused bucket-scan + LDS histogram + block scan -> off/dinv,
//                         then in-LDS scatter -> col)
//   Per layer: g = (h @ W) * dinv [fp16] ; h = act(dinv * sum_{N(d)+self} g[s] + b)
// R13 (resubmit; prior bench failed on GPU acquisition):
//      agg node-concurrency x2 again (confirmed lever, R11 -23us):
//      agg64 = 4 nodes/wave (16 lanes x half4, 8B loads; load insts/edge halved),
//      agg32 = 8 nodes/wave (8 lanes x half4). Unroll back to 4 chains (R12's
//      8-deep was null: mean degree ~16 -> tail-dominated).
// NOTE: packing assumes N <= 65535 (here N=50000).

#define IN_DIM 64
#define HID_DIM 64
#define LAT_DIM 32
#define BCAP 5120   // bucket capacity: mean 4081, sigma ~64 -> +16 sigma

typedef __attribute__((ext_vector_type(8))) _Float16 half8;
typedef __attribute__((ext_vector_type(4))) _Float16 half4;

// ---------------- bucketed CSR construction ----------------

__global__ __launch_bounds__(256) void bin_kernel(const int* __restrict__ src,
                                                  const int* __restrict__ dst,
                                                  int* __restrict__ bucket_cnt,
                                                  unsigned* __restrict__ pairs, int E) {
    __shared__ int bcnt[256];
    __shared__ int bbase[256];
    int tid = threadIdx.x;
    bcnt[tid] = 0;
    __syncthreads();
    int base = blockIdx.x * 4096;
    unsigned pk[16]; int bk[16]; int rk[16];
    #pragma unroll
    for (int i = 0; i < 16; ++i) {
        int e = base + i * 256 + tid;
        bk[i] = -1;
        if (e < E) {
            int s = __builtin_nontemporal_load(src + e);
            int d = __builtin_nontemporal_load(dst + e);
            bk[i] = d >> 8;
            pk[i] = (unsigned)s | ((unsigned)(d & 255) << 16);
            rk[i] = atomicAdd(&bcnt[bk[i]], 1);
        }
    }
    __syncthreads();
    int c = bcnt[tid];
    if (c > 0) bbase[tid] = atomicAdd(&bucket_cnt[tid], c);
    __syncthreads();
    #pragma unroll
    for (int i = 0; i < 16; ++i) {
        if (bk[i] >= 0) {
            int pos = bbase[bk[i]] + rk[i];
            if (pos < BCAP) pairs[(size_t)bk[i] * BCAP + pos] = pk[i];
        }
    }
}

// Fused: (A) every block scans all bucket counts in LDS (cheap, redundant),
// (B) per-bucket node histogram, (C) block scan -> off/dinv, (D) in-LDS scatter.
__global__ __launch_bounds__(256) void build_csr_kernel(const unsigned* __restrict__ pairs,
                                                        const int* __restrict__ bucket_cnt,
                                                        int* __restrict__ off,
                                                        float* __restrict__ dinv,
                                                        int* __restrict__ col,
                                                        int N, int NBK) {
    __shared__ int sboff[256];
    __shared__ int h[256];
    __shared__ int scur[256];
    __shared__ int wtot[4];
    int b = blockIdx.x, tid = threadIdx.x;
    int lane = tid & 63, wid = tid >> 6;

    // A: exclusive scan of bucket counts
    int v = (tid < NBK) ? min(bucket_cnt[tid], BCAP) : 0;
    int sc = v;
    #pragma unroll
    for (int d = 1; d < 64; d <<= 1) {
        int t = __shfl_up(sc, d, 64);
        if (lane >= d) sc += t;
    }
    if (lane == 63) wtot[wid] = sc;
    h[tid] = 0;
    __syncthreads();
    int woff = 0;
    #pragma unroll
    for (int w = 0; w < 4; ++w) if (w < wid) woff += wtot[w];
    sboff[tid] = woff + sc - v;
    __syncthreads();
    int boff_b = sboff[b];

    // B: histogram of this bucket's local dst
    int c = min(bucket_cnt[b], BCAP);
    const unsigned* pb = pairs + (size_t)b * BCAP;
    for (int i = tid; i < c; i += 256)
        atomicAdd(&h[pb[i] >> 16], 1);
    __syncthreads();

    // C: block scan of histogram -> off / dinv / scur
    int hv = h[tid];
    int sc2 = hv;
    #pragma unroll
    for (int d = 1; d < 64; d <<= 1) {
        int t = __shfl_up(sc2, d, 64);
        if (lane >= d) sc2 += t;
    }
    if (lane == 63) wtot[wid] = sc2;
    __syncthreads();
    int woff2 = 0;
    #pragma unroll
    for (int w = 0; w < 4; ++w) if (w < wid) woff2 += wtot[w];
    int incl = woff2 + sc2;
    int node = b * 256 + tid;
    scur[tid] = boff_b + incl - hv;
    if (node < N) {
        off[node + 1] = boff_b + incl;
        dinv[node]    = rsqrtf((float)(hv + 1));
    }
    if (b == 0 && tid == 0) off[0] = 0;
    __syncthreads();

    // D: scatter (col writes land in this bucket's contiguous window)
    for (int i = tid; i < c; i += 256) {
        unsigned p = pb[i];
        int pos = atomicAdd(&scur[p >> 16], 1);
        col[pos] = (int)(p & 0xFFFFu);
    }
}

// ---------------- GEMM (N x 64) @ (64 x OUT) * dinv[row] -> fp16 G ----------------
// Row-major X staging (coalesced). 4x4 outputs/thread; a-reads are 16-lane
// broadcasts (free), b-read one 2-way b128 (free).

template<int OUT, int RT, typename TIN>
__global__ __launch_bounds__(256) void gemm_tile_kernel(const TIN* __restrict__ X,
                                                        const float* __restrict__ W,
                                                        const float* __restrict__ dinv,
                                                        _Float16* __restrict__ G, int N) {
    constexpr int CG = OUT / 4;
    static_assert(256 / CG * 4 == RT, "RT must match 4*(256/CG)");
    __shared__ float Ws[64 * OUT];
    __shared__ float Xs[RT][64 + 4];
    int tid = threadIdx.x;
    int row0 = blockIdx.x * RT;

    for (int f = 4 * tid; f < 64 * OUT; f += 1024)
        *(float4*)&Ws[f] = *(const float4*)&W[f];

    if constexpr (std::is_same<TIN, float>::value) {
        for (int f = 4 * tid; f < RT * 64; f += 1024) {
            int r = f >> 6, k0 = f & 63, gr = row0 + r;
            float4 v = (gr < N) ? *(const float4*)&X[(size_t)gr * 64 + k0]
                                : make_float4(0.f, 0.f, 0.f, 0.f);
            *(float4*)&Xs[r][k0] = v;
        }
    } else {
        for (int f = 8 * tid; f < RT * 64; f += 2048) {
            int r = f >> 6, k0 = f & 63, gr = row0 + r;
            if (gr < N) {
                half8 v = *(const half8*)&X[(size_t)gr * 64 + k0];
                #pragma unroll
                for (int i = 0; i < 8; ++i) Xs[r][k0 + i] = (float)v[i];
            } else {
                #pragma unroll
                for (int i = 0; i < 8; ++i) Xs[r][k0 + i] = 0.f;
            }
        }
    }
    __syncthreads();

    int cr = tid % CG;
    int rr = tid / CG;
    float acc[4][4] = {};
    #pragma unroll 4
    for (int k = 0; k < 64; ++k) {
        float4 bv = *(float4*)&Ws[k * OUT + 4 * cr];
        float av[4] = {Xs[4 * rr + 0][k], Xs[4 * rr + 1][k],
                       Xs[4 * rr + 2][k], Xs[4 * rr + 3][k]};
        float bb[4] = {bv.x, bv.y, bv.z, bv.w};
        #pragma unroll
        for (int j = 0; j < 4; ++j)
            #pragma unroll
            for (int i = 0; i < 4; ++i)
                acc[j][i] += av[j] * bb[i];
    }

    #pragma unroll
    for (int j = 0; j < 4; ++j) {
        int gr = row0 + 4 * rr + j;
        if (gr < N) {
            float s = dinv[gr];
            half4 o;
            #pragma unroll
            for (int i = 0; i < 4; ++i) o[i] = (_Float16)(acc[j][i] * s);
            *(half4*)&G[(size_t)gr * OUT + 4 * cr] = o;
        }
    }
}

// ---------------- CSR aggregation, half4 lanes, multi-node waves ----------------
// D=64: 4 nodes/wave. 16 lanes per node, each lane owns one half4 (8B); a row
// is 16 lanes x 8B = 128B coalesced. 4 independent accumulator chains. Per edge
// per node: 16 load-insts (was 32 at half2) -> half the issue, 2x concurrent
// nodes/CU vs R11. Degree divergence across the 4 sub-nodes is exec-masked.

template<bool TANH>
__global__ __launch_bounds__(256) void agg64_kernel(const _Float16* __restrict__ G,
                           const int* __restrict__ off, const int* __restrict__ col,
                           const float* __restrict__ dinv, const float* __restrict__ b,
                           _Float16* __restrict__ H, int N) {
    int tid  = threadIdx.x;
    int lane = tid & 63;
    int w    = tid >> 6;
    int q    = lane >> 4;                       // node within wave (0..3)
    int l4   = lane & 15;                       // half4 col index (row = 16 half4)
    int node = (blockIdx.x * 4 + w) * 4 + q;
    if (node >= N) return;
    const half4* Gv = (const half4*)G;
    int p  = off[node];
    int p1 = off[node + 1];
    float a0[4], a1[4], a2[4], a3[4];
    {   // self loop
        half4 u = Gv[(size_t)node * 16 + l4];
        #pragma unroll
        for (int i = 0; i < 4; ++i) { a0[i] = (float)u[i]; a1[i] = 0.f; a2[i] = 0.f; a3[i] = 0.f; }
    }
    for (; p + 3 < p1; p += 4) {
        int s0 = col[p], s1 = col[p + 1], s2 = col[p + 2], s3 = col[p + 3];
        half4 u0 = Gv[(size_t)s0 * 16 + l4];
        half4 u1 = Gv[(size_t)s1 * 16 + l4];
        half4 u2 = Gv[(size_t)s2 * 16 + l4];
        half4 u3 = Gv[(size_t)s3 * 16 + l4];
        #pragma unroll
        for (int i = 0; i < 4; ++i) {
            a0[i] += (float)u0[i]; a1[i] += (float)u1[i];
            a2[i] += (float)u2[i]; a3[i] += (float)u3[i];
        }
    }
    for (; p < p1; ++p) {
        half4 u = Gv[(size_t)col[p] * 16 + l4];
        #pragma unroll
        for (int i = 0; i < 4; ++i) a0[i] += (float)u[i];
    }
    float dn = dinv[node];
    half4 o;
    #pragma unroll
    for (int i = 0; i < 4; ++i) {
        float v = dn * ((a0[i] + a1[i]) + (a2[i] + a3[i])) + b[4 * l4 + i];
        if (TANH) v = tanhf(v);
        o[i] = (_Float16)v;
    }
    ((half4*)H)[(size_t)node * 16 + l4] = o;
}

// D=32 final layer: 8 nodes/wave (8 lanes x half4 each), f32 float4 output.
__global__ __launch_bounds__(256) void agg32_kernel(const _Float16* __restrict__ G,
                           const int* __restrict__ off, const int* __restrict__ col,
                           const float* __restrict__ dinv, const float* __restrict__ b,
                           float* __restrict__ H, int N) {
    int tid  = threadIdx.x;
    int lane = tid & 63;
    int w    = tid >> 6;
    int q    = lane >> 3;                       // node within wave (0..7)
    int l4   = lane & 7;                        // half4 col index (row = 8 half4)
    int node = (blockIdx.x * 4 + w) * 8 + q;
    if (node >= N) return;
    const half4* Gv = (const half4*)G;
    int p  = off[node];
    int p1 = off[node + 1];
    float a0[4], a1[4], a2[4], a3[4];
    {   // self loop
        half4 u = Gv[(size_t)node * 8 + l4];
        #pragma unroll
        for (int i = 0; i < 4; ++i) { a0[i] = (float)u[i]; a1[i] = 0.f; a2[i] = 0.f; a3[i] = 0.f; }
    }
    for (; p + 3 < p1; p += 4) {
        int s0 = col[p], s1 = col[p + 1], s2 = col[p + 2], s3 = col[p + 3];
        half4 u0 = Gv[(size_t)s0 * 8 + l4];
        half4 u1 = Gv[(size_t)s1 * 8 + l4];
        half4 u2 = Gv[(size_t)s2 * 8 + l4];
        half4 u3 = Gv[(size_t)s3 * 8 + l4];
        #pragma unroll
        for (int i = 0; i < 4; ++i) {
            a0[i] += (float)u0[i]; a1[i] += (float)u1[i];
            a2[i] += (float)u2[i]; a3[i] += (float)u3[i];
        }
    }
    for (; p < p1; ++p) {
        half4 u = Gv[(size_t)col[p] * 8 + l4];
        #pragma unroll
        for (int i = 0; i < 4; ++i) a0[i] += (float)u[i];
    }
    float dn = dinv[node];
    float4 o;
    o.x = dn * ((a0[0] + a1[0]) + (a2[0] + a3[0])) + b[4 * l4 + 0];
    o.y = dn * ((a0[1] + a1[1]) + (a2[1] + a3[1])) + b[4 * l4 + 1];
    o.z = dn * ((a0[2] + a1[2]) + (a2[2] + a3[2])) + b[4 * l4 + 2];
    o.w = dn * ((a0[3] + a1[3]) + (a2[3] + a3[3])) + b[4 * l4 + 3];
    *(float4*)&H[(size_t)node * 32 + 4 * l4] = o;
}

// ---------------- launch ----------------

static inline size_t align256(size_t x) { return (x + 255) & ~(size_t)255; }

extern "C" void kernel_launch(void* const* d_in, const int* in_sizes, int n_in,
                              void* d_out, int out_size, void* d_ws, size_t ws_size,
                              hipStream_t stream) {
    const float* x   = (const float*)d_in[0];
    const int*   ei  = (const int*)d_in[1];
    const float* W1  = (const float*)d_in[2];
    const float* b1  = (const float*)d_in[3];
    const float* W2  = (const float*)d_in[4];
    const float* b2  = (const float*)d_in[5];
    const float* W3  = (const float*)d_in[6];
    const float* b3  = (const float*)d_in[7];
    float* out = (float*)d_out;

    const int N = in_sizes[0] / IN_DIM;   // 50000
    const int E = in_sizes[1] / 2;        // 800000
    const int* src = ei;
    const int* dst = ei + E;
    const int NBK  = (N + 255) / 256;     // buckets (196)
    const int BINB = (E + 4095) / 4096;   // bin blocks (196)

    // workspace layout
    char* ws = (char*)d_ws;
    size_t o = 0;
    int*       bkcnt = (int*)(ws + o);       o = align256(o + 256 * 4);
    int*       off   = (int*)(ws + o);       o = align256(o + (size_t)(N + 1) * 4);
    float*     dinv  = (float*)(ws + o);     o = align256(o + (size_t)N * 4);
    unsigned*  pairs = (unsigned*)(ws + o);  o = align256(o + (size_t)NBK * BCAP * 4);
    int*       col   = (int*)(ws + o);       o = align256(o + (size_t)E * 4);
    _Float16*  bufG  = (_Float16*)(ws + o);  o = align256(o + (size_t)N * HID_DIM * 2);
    _Float16*  bufH  = (_Float16*)(ws + o);  o = align256(o + (size_t)N * HID_DIM * 2);
    (void)ws_size;

    // CSR build
    hipMemsetAsync(bkcnt, 0, 256 * 4, stream);
    bin_kernel<<<BINB, 256, 0, stream>>>(src, dst, bkcnt, pairs, E);
    build_csr_kernel<<<NBK, 256, 0, stream>>>(pairs, bkcnt, off, dinv, col, N, NBK);

    const int g64_grid   = (N + 63) / 64;    // RT=64
    const int g32_grid   = (N + 127) / 128;  // RT=128
    const int agg64_grid = (N + 15) / 16;    // 4 nodes/wave, 4 waves/block
    const int agg32_grid = (N + 31) / 32;    // 8 nodes/wave, 4 waves/block

    // layer 1
    gemm_tile_kernel<HID_DIM, 64, float><<<g64_grid, 256, 0, stream>>>(x, W1, dinv, bufG, N);
    agg64_kernel<true><<<agg64_grid, 256, 0, stream>>>(bufG, off, col, dinv, b1, bufH, N);
    // layer 2
    gemm_tile_kernel<HID_DIM, 64, _Float16><<<g64_grid, 256, 0, stream>>>(bufH, W2, dinv, bufG, N);
    agg64_kernel<true><<<agg64_grid, 256, 0, stream>>>(bufG, off, col, dinv, b2, bufH, N);
    // layer 3 (D=32, f32 out)
    gemm_tile_kernel<LAT_DIM, 128, _Float16><<<g32_grid, 256, 0, stream>>>(bufH, W3, dinv, bufG, N);
    agg32_kernel<<<agg32_grid, 256, 0, stream>>>(bufG, off, col, dinv, b3, out, N);
}